// Round 1
// 438.214 us; speedup vs baseline: 1.0526x; 1.0526x over previous
//
#include <hip/hip_runtime.h>
#include <hip/hip_bf16.h>

// ---------------- problem constants ----------------
#define NI 1152
// conv2 GEMM view: M=9216 as (pos,b)=36*256; N=256 (oc); K=81 taps x 256 ic

typedef __attribute__((ext_vector_type(8))) _Float16 f16x8;
typedef __attribute__((ext_vector_type(4))) float f32x4;
typedef __attribute__((ext_vector_type(8))) unsigned short u16x8;
typedef __attribute__((ext_vector_type(4))) unsigned short u16x4;

// ws layout (bytes). Phase-1 buffers (w6,h3,wT1,pp) alias under uhat (94.4MB):
static const size_t UHAT_OFF = 0;                        // bf16 1152*10*256*16 = 94,371,840
static const size_t W6_OFF   = 0;                        // f16 81*8*16*64*8 = 10,616,832 B
static const size_t H3_OFF   = 10747904UL;               // f16 8*400*4*256*8 = 52,428,800 B
static const size_t WT1_OFF  = 63176704UL;               // f32 81*256
static const size_t PP_OFF   = 63259648UL;               // f32 9216*256 (ends 72.7MB < 94.4MB)
static const size_t U_OFF    = 94371840UL;               // f32 u[i][b][d]
static const size_t SP_OFF   = 103809024UL;              // f32 144*256*160
static const size_t L_OFF    = 127401984UL;              // f32 256*1152*10
static const size_t V_OFF    = 139198464UL;              // f32 256*160

__device__ __forceinline__ unsigned short f2bf(float x) {
    unsigned u = __builtin_bit_cast(unsigned, x);
    u += 0x7fffu + ((u >> 16) & 1u);
    return (unsigned short)(u >> 16);
}
__device__ __forceinline__ float bf2f(unsigned short h) {
    return __builtin_bit_cast(float, (unsigned)h << 16);
}
__device__ __forceinline__ void atomAddF(float* p, float v) {
    __hip_atomic_fetch_add(p, v, __ATOMIC_RELAXED, __HIP_MEMORY_SCOPE_AGENT);
}

// ---------------- weight prep: pc_w [oc][ic*81+tap] -> w6 frag-linear ----------------
// w6 linear: (((tap*8+ks)*16 + og)*64 + lane)*8 + icl
//   og=oc>>4, fr=oc&15, lane=kch*16+fr, ic=ks*32+kch*8+icl
__global__ __launch_bounds__(256) void k_prep_w(const float* __restrict__ pcw,
                                                _Float16* __restrict__ w6) {
    __shared__ float sl[5184];
    int oc  = blockIdx.x;       // 256
    int ic0 = blockIdx.y * 64;  // 4 chunks
    const float* src = pcw + (size_t)oc * 20736 + (size_t)ic0 * 81;
    for (int j = threadIdx.x; j < 5184; j += 256) sl[j] = src[j];
    __syncthreads();
    int og = oc >> 4, fr = oc & 15;
    for (int t = threadIdx.x; t < 5184; t += 256) {
        int tap = t >> 6, i = t & 63;
        int ic = ic0 + i;
        int ks = ic >> 5, kch = (ic >> 3) & 3, icl = ic & 7;
        int lane = kch * 16 + fr;
        w6[(((size_t)(tap * 8 + ks) * 16 + og) * 64 + lane) * 8 + icl] =
            (_Float16)sl[i * 81 + tap];
    }
}

// conv1_w [oc][81] -> wT1 [t][oc]
__global__ void k_transpose_w1(const float* __restrict__ w, float* __restrict__ wT) {
    int t = blockIdx.x, oc = threadIdx.x;
    wT[t * 256 + oc] = w[oc * 81 + t];
}

// ---------------- conv1 + relu -> h3[ks][y][x][p][b][8] f16 ----------------
__global__ __launch_bounds__(256) void k_conv1(const float* __restrict__ x,
                                               const float* __restrict__ wT1,
                                               const float* __restrict__ bias,
                                               _Float16* __restrict__ h3) {
    __shared__ _Float16 hs[2][20][256];  // 20KB
    int b  = blockIdx.y;    // 256
    int rp = blockIdx.x;    // 10 row-pairs
    int oc = threadIdx.x;   // 256
    int oy0 = rp * 2;
    const float* xb = x + (size_t)b * 784;
    float bv = bias[oc];
    float acc0[20], acc1[20];
#pragma unroll
    for (int i = 0; i < 20; ++i) { acc0[i] = bv; acc1[i] = bv; }
    for (int ky = 0; ky < 9; ++ky) {
        const float* r0 = xb + (oy0 + ky) * 28;
        const float* r1 = r0 + 28;
        float x0[28], x1[28];
#pragma unroll
        for (int c = 0; c < 28; ++c) { x0[c] = r0[c]; x1[c] = r1[c]; }
#pragma unroll
        for (int kx = 0; kx < 9; ++kx) {
            float w = wT1[(ky * 9 + kx) * 256 + oc];
#pragma unroll
            for (int px = 0; px < 20; ++px) {
                acc0[px] += x0[px + kx] * w;
                acc1[px] += x1[px + kx] * w;
            }
        }
    }
#pragma unroll
    for (int px = 0; px < 20; ++px) {
        hs[0][px][oc] = (_Float16)fmaxf(acc0[px], 0.f);
        hs[1][px][oc] = (_Float16)fmaxf(acc1[px], 0.f);
    }
    __syncthreads();
    for (int cid = threadIdx.x; cid < 1280; cid += 256) {
        int kp = cid & 31;          // ks*4 + p
        int pos = cid >> 5;         // ry*20 + px
        int ry = pos / 20, px2 = pos % 20;
        int ks = kp >> 2, p = kp & 3;
        f16x8 val = *(const f16x8*)&hs[ry][px2][ks * 32 + p * 8];
        _Float16* dst = h3 + ((size_t)((ks * 400 + (oy0 + ry) * 20 + px2) * 4 + p) * 256 + b) * 8;
        *(f16x8*)dst = val;
    }
}

// ---------------- primary caps conv: LDS-free direct-register MFMA pipeline ----------------
// grid 1152 flat; block 256 = 4 waves (2x2), wave tile 64x64.
// XCD-affinity swizzle on the split-K axis: ks = blockIdx.x & 7, so under the
// round-robin block->XCD mapping each XCD owns exactly one ks slice. Per-XCD L2
// working set drops from h3+w6 (63MB) to one slice (6.5MB h3 + 1.3MB w6), and
// co-resident blocks stream taps in near-lockstep -> per-tap active set ~0.6MB.
// Both operands fragment-contiguous in global (A: 4x256B, B: 1KB per frag-load).
// 3-buffer distance-2 register pipeline; no LDS, no barriers; vmcnt never drains to 0.
__global__ __launch_bounds__(256, 2) void k_conv2_direct(
    const _Float16* __restrict__ h3, const _Float16* __restrict__ w6,
    float* __restrict__ pp) {
    const int blk = blockIdx.x;
    const int ks = blk & 7;          // XCD = ks (round-robin %8)
    const int rest = blk >> 3;       // 0..143
    const int mt = rest % 72;        // consecutive co-resident blocks: consecutive mt
    const int nt = rest / 72;        // same nt -> same B panel on an XCD cohort
    const int pos = mt >> 1, bhalf = mt & 1;
    const int py = pos / 6, px = pos % 6;
    const int l = threadIdx.x & 63;
    const int w = threadIdx.x >> 6;
    const int wm = w >> 1, wn = w & 1;
    const int p = l >> 4, fr = l & 15;

    // A lane base (element offsets, excl. tap window): + (y*20+x)*8192 + mi*128
    const _Float16* abase = h3 + (size_t)ks * 3276800 + p * 2048 +
                            (bhalf * 128 + wm * 64 + fr) * 8;
    // B lane base: + (tap*8+ks)*8192 + ni*512
    const _Float16* bbase = w6 + (nt * 8 + wn * 4) * 512 + l * 8;

    f16x8 a[3][4], b[3][4];
    f32x4 acc[4][4];
    const f32x4 z = {0.f, 0.f, 0.f, 0.f};
#pragma unroll
    for (int mi = 0; mi < 4; ++mi)
#pragma unroll
        for (int ni = 0; ni < 4; ++ni) acc[mi][ni] = z;

#define LOADAB(buf, tap)                                                       \
    do {                                                                       \
        const int _t = (tap);                                                  \
        const int _y = _t / 9, _x = _t - _y * 9;                               \
        const _Float16* _ab = abase + ((2 * py + _y) * 20 + (2 * px + _x)) * 8192; \
        a[buf][0] = *(const f16x8*)(_ab);                                      \
        a[buf][1] = *(const f16x8*)(_ab + 128);                                \
        a[buf][2] = *(const f16x8*)(_ab + 256);                                \
        a[buf][3] = *(const f16x8*)(_ab + 384);                                \
        const _Float16* _bb = bbase + (size_t)(_t * 8 + ks) * 8192;            \
        b[buf][0] = *(const f16x8*)(_bb);                                      \
        b[buf][1] = *(const f16x8*)(_bb + 512);                                \
        b[buf][2] = *(const f16x8*)(_bb + 1024);                               \
        b[buf][3] = *(const f16x8*)(_bb + 1536);                               \
    } while (0)

#define MFMA_ALL(buf)                                                          \
    do {                                                                       \
        _Pragma("unroll") for (int mi = 0; mi < 4; ++mi)                       \
            _Pragma("unroll") for (int ni = 0; ni < 4; ++ni)                   \
                acc[mi][ni] = __builtin_amdgcn_mfma_f32_16x16x32_f16(          \
                    a[buf][mi], b[buf][ni], acc[buf == buf ? mi : mi][ni], 0, 0, 0); \
    } while (0)

    // NOTE: acc index expression above is just acc[mi][ni]; kept plain below.
#undef MFMA_ALL
#define MFMA_ALL(buf)                                                          \
    do {                                                                       \
        _Pragma("unroll") for (int mi = 0; mi < 4; ++mi)                       \
            _Pragma("unroll") for (int ni = 0; ni < 4; ++ni)                   \
                acc[mi][ni] = __builtin_amdgcn_mfma_f32_16x16x32_f16(          \
                    a[buf][mi], b[buf][ni], acc[mi][ni], 0, 0, 0);             \
    } while (0)

    LOADAB(0, 0);
    LOADAB(1, 1);
    for (int k = 0; k < 27; ++k) {
        const int t0 = 3 * k;
        LOADAB(2, t0 + 2);           // t0+2 <= 80 always
        MFMA_ALL(0);
        if (t0 + 3 < 81) LOADAB(0, t0 + 3);
        MFMA_ALL(1);
        if (t0 + 4 < 81) LOADAB(1, t0 + 4);
        MFMA_ALL(2);
    }
#undef LOADAB
#undef MFMA_ALL

    // epilogue: D[m][n], m=(lane>>4)*4+reg, n=lane&15; atomic split-K reduce
    const int row0 = (l >> 4) * 4;
    const int ncol = l & 15;
#pragma unroll
    for (int mi = 0; mi < 4; ++mi)
#pragma unroll
        for (int ni = 0; ni < 4; ++ni) {
            int n = nt * 128 + wn * 64 + ni * 16 + ncol;
#pragma unroll
            for (int reg = 0; reg < 4; ++reg) {
                int m = pos * 256 + bhalf * 128 + wm * 64 + mi * 16 + row0 + reg;
                atomAddF(&pp[(size_t)m * 256 + n], acc[mi][ni][reg]);
            }
        }
}

// ---------------- bias + primary squash -> u[i][b][d]  (pp m-order = pos*256+b) ----------------
__global__ __launch_bounds__(256) void k_sum_squash2(const float* __restrict__ pp,
                                                     const float* __restrict__ bias,
                                                     float* __restrict__ u) {
    int m = blockIdx.x * 8 + (threadIdx.x >> 5);
    int cap = threadIdx.x & 31;
    const float* p0 = pp + (size_t)m * 256 + cap * 8;
    float s[8], sq = 0.f;
#pragma unroll
    for (int d = 0; d < 8; ++d) {
        float a = p0[d] + bias[cap * 8 + d];
        sq += a * a; s[d] = a;
    }
    float scale = sq / ((1.0f + sq) * sqrtf(sq + 1e-8f));
    int pos = m >> 8, b = m & 255;
    int i = cap * 36 + pos;
    float* up = u + ((size_t)i * 256 + b) * 8;
    ((float4*)up)[0] = make_float4(scale * s[0], scale * s[1], scale * s[2], scale * s[3]);
    ((float4*)up)[1] = make_float4(scale * s[4], scale * s[5], scale * s[6], scale * s[7]);
}

// ---------------- build u_hat (bf16) [i][j][b][o] ----------------
__global__ __launch_bounds__(256) void k_build_uhat(const float* __restrict__ u,
                                                    const float* __restrict__ W,
                                                    unsigned short* __restrict__ UH) {
    __shared__ float Ws[1280];
    int i = blockIdx.x;  // 1152
    for (int t = threadIdx.x; t < 1280; t += 256) Ws[t] = W[(size_t)i * 1280 + t];
    __syncthreads();
    int b = threadIdx.x;  // 256
    const float* uptr = u + ((size_t)i * 256 + b) * 8;
    float u8[8];
    ((float4*)u8)[0] = ((const float4*)uptr)[0];
    ((float4*)u8)[1] = ((const float4*)uptr)[1];
#pragma unroll
    for (int j = 0; j < 10; ++j) {
        float o16[16];
#pragma unroll
        for (int o = 0; o < 16; ++o) o16[o] = 0.f;
#pragma unroll
        for (int d = 0; d < 8; ++d) {
            const float* wp = Ws + d * 160 + j * 16;
#pragma unroll
            for (int o = 0; o < 16; ++o) o16[o] += u8[d] * wp[o];
        }
        u16x8 h0, h1;
#pragma unroll
        for (int o = 0; o < 8; ++o) { h0[o] = f2bf(o16[o]); h1[o] = f2bf(o16[8 + o]); }
        unsigned short* dst = UH + ((size_t)(i * 10 + j) * 256 + b) * 16;
        *(u16x8*)dst = h0;
        *(u16x8*)(dst + 8) = h1;
    }
}

// ---------------- routing iter 0: s0 = 0.1 * sum_i u_hat ----------------
__global__ __launch_bounds__(256) void k_route_s0(const unsigned short* __restrict__ UH,
                                                  float* __restrict__ SP) {
    int it = blockIdx.x, bt = blockIdx.y;
    int b0 = bt * 64, i0 = it * 8;
    int b_l = threadIdx.x & 63;
    int og = __builtin_amdgcn_readfirstlane((int)(threadIdx.x >> 6));
    float acc[10][4];
#pragma unroll
    for (int j = 0; j < 10; ++j)
#pragma unroll
        for (int o = 0; o < 4; ++o) acc[j][o] = 0.f;
    for (int li = 0; li < 8; ++li) {
        const unsigned short* up = UH + ((size_t)(i0 + li) * 10 * 256 + b0 + b_l) * 16 + og * 4;
#pragma unroll
        for (int j = 0; j < 10; ++j) {
            u16x4 t = *(const u16x4*)(up + j * 4096);
#pragma unroll
            for (int o = 0; o < 4; ++o) acc[j][o] += bf2f(t[o]);
        }
    }
    float* sp = SP + ((size_t)it * 256 + b0 + b_l) * 160 + og * 4;
#pragma unroll
    for (int j = 0; j < 10; ++j)
        *(float4*)(sp + j * 16) = make_float4(0.1f * acc[j][0], 0.1f * acc[j][1],
                                              0.1f * acc[j][2], 0.1f * acc[j][3]);
}

// ---------------- fused routing: logits (+)= <u_hat,v>; softmax; s-partials ----------------
// grid (144,4); block 256. add=0: L := agreement (prior logits zero). storeL: write L back.
__global__ __launch_bounds__(256) void k_route_as(float* __restrict__ L,
                                                  const unsigned short* __restrict__ UH,
                                                  const float* __restrict__ V,
                                                  float* __restrict__ SP,
                                                  int add, int storeL) {
    __shared__ float VL[64][165];
    __shared__ float LG[64][81];
    int it = blockIdx.x, bt = blockIdx.y;
    int b0 = bt * 64, i0 = it * 8;
    int b_l = threadIdx.x & 63;
    int ig = __builtin_amdgcn_readfirstlane((int)(threadIdx.x >> 6));
    int b_r = threadIdx.x >> 2, part = threadIdx.x & 3;
    {
        const float4* vsrc = (const float4*)(V + (size_t)(b0 + b_r) * 160 + part * 40);
#pragma unroll
        for (int q = 0; q < 10; ++q) {
            float4 vv = vsrc[q]; int c = part * 40 + q * 4;
            VL[b_r][c] = vv.x; VL[b_r][c + 1] = vv.y; VL[b_r][c + 2] = vv.z; VL[b_r][c + 3] = vv.w;
        }
        if (add) {
            const float4* lsrc = (const float4*)(L + (size_t)(b0 + b_r) * 11520 + i0 * 10 + part * 20);
#pragma unroll
            for (int q = 0; q < 5; ++q) {
                float4 t = lsrc[q]; int c = part * 20 + q * 4;
                LG[b_r][c] = t.x; LG[b_r][c + 1] = t.y; LG[b_r][c + 2] = t.z; LG[b_r][c + 3] = t.w;
            }
        }
    }
    __syncthreads();
    // agreement phase: thread group ig handles 2 i's
#pragma unroll
    for (int ii = 0; ii < 2; ++ii) {
        int il = ig * 2 + ii;
        int i = i0 + il;
        const unsigned short* up = UH + ((size_t)i * 10 * 256 + b0 + b_l) * 16;
#pragma unroll
        for (int j = 0; j < 10; ++j) {
            u16x8 ua = *(const u16x8*)(up + j * 4096);
            u16x8 ub = *(const u16x8*)(up + j * 4096 + 8);
            float a = 0.f;
#pragma unroll
            for (int o = 0; o < 8; ++o) a += bf2f(ua[o]) * VL[b_l][j * 16 + o];
#pragma unroll
            for (int o = 0; o < 8; ++o) a += bf2f(ub[o]) * VL[b_l][j * 16 + 8 + o];
            float base = add ? LG[b_l][il * 10 + j] : 0.f;
            LG[b_l][il * 10 + j] = base + a;
        }
    }
    __syncthreads();
    if (storeL) {
        float4* ldst = (float4*)(L + (size_t)(b0 + b_r) * 11520 + i0 * 10 + part * 20);
#pragma unroll
        for (int q = 0; q < 5; ++q) {
            int c = part * 20 + q * 4;
            ldst[q] = make_float4(LG[b_r][c], LG[b_r][c + 1], LG[b_r][c + 2], LG[b_r][c + 3]);
        }
    }
    // s phase: softmax of fresh logits, accumulate c * u_hat (og = ig reuse)
    float acc[10][4];
#pragma unroll
    for (int j = 0; j < 10; ++j)
#pragma unroll
        for (int o = 0; o < 4; ++o) acc[j][o] = 0.f;
    for (int li = 0; li < 8; ++li) {
        float lg[10];
#pragma unroll
        for (int j = 0; j < 10; ++j) lg[j] = LG[b_l][li * 10 + j];
        float m = lg[0];
#pragma unroll
        for (int j = 1; j < 10; ++j) m = fmaxf(m, lg[j]);
        float e[10], ssum = 0.f;
#pragma unroll
        for (int j = 0; j < 10; ++j) { e[j] = __expf(lg[j] - m); ssum += e[j]; }
        float inv = 1.0f / ssum;
        const unsigned short* up = UH + ((size_t)(i0 + li) * 10 * 256 + b0 + b_l) * 16 + ig * 4;
#pragma unroll
        for (int j = 0; j < 10; ++j) {
            float cj = e[j] * inv;
            u16x4 t = *(const u16x4*)(up + j * 4096);
#pragma unroll
            for (int o = 0; o < 4; ++o) acc[j][o] += cj * bf2f(t[o]);
        }
    }
    float* sp = SP + ((size_t)it * 256 + b0 + b_l) * 160 + ig * 4;
#pragma unroll
    for (int j = 0; j < 10; ++j)
        *(float4*)(sp + j * 16) = make_float4(acc[j][0], acc[j][1], acc[j][2], acc[j][3]);
}

// ---------------- routing: reduce partials + squash -> v ----------------
__global__ __launch_bounds__(256) void k_route_v(const float* __restrict__ SP,
                                                 float* __restrict__ vout) {
    int n = blockIdx.x * 256 + threadIdx.x;  // 40960
    float ssum = 0.f;
    for (int t = 0; t < 144; ++t) ssum += SP[(size_t)t * 40960 + n];
    float sq = ssum * ssum;
    float tot = sq;
#pragma unroll
    for (int mask = 1; mask < 16; mask <<= 1) tot += __shfl_xor(tot, mask, 64);
    float scale = tot / ((1.0f + tot) * sqrtf(tot + 1e-8f));
    vout[n] = scale * ssum;
}

// ---------------- launcher ----------------
extern "C" void kernel_launch(void* const* d_in, const int* in_sizes, int n_in,
                              void* d_out, int out_size, void* d_ws, size_t ws_size,
                              hipStream_t stream) {
    (void)in_sizes; (void)n_in; (void)out_size; (void)ws_size;
    const float* x   = (const float*)d_in[0];
    const float* c1w = (const float*)d_in[1];
    const float* c1b = (const float*)d_in[2];
    const float* pcw = (const float*)d_in[3];
    const float* pcb = (const float*)d_in[4];
    const float* Wd  = (const float*)d_in[5];
    float* out = (float*)d_out;
    char* wsb  = (char*)d_ws;

    unsigned short* uh = (unsigned short*)(wsb + UHAT_OFF);
    _Float16* w6 = (_Float16*)(wsb + W6_OFF);
    _Float16* h3 = (_Float16*)(wsb + H3_OFF);
    float* wT1 = (float*)(wsb + WT1_OFF);
    float* pp  = (float*)(wsb + PP_OFF);
    float* u   = (float*)(wsb + U_OFF);
    float* sp  = (float*)(wsb + SP_OFF);
    float* lg  = (float*)(wsb + L_OFF);
    float* v   = (float*)(wsb + V_OFF);

    hipMemsetAsync(pp, 0, (size_t)9216 * 256 * sizeof(float), stream);

    k_prep_w<<<dim3(256, 4), 256, 0, stream>>>(pcw, w6);
    k_transpose_w1<<<81, 256, 0, stream>>>(c1w, wT1);
    k_conv1<<<dim3(10, 256), 256, 0, stream>>>(x, wT1, c1b, h3);
    k_conv2_direct<<<dim3(1152), 256, 0, stream>>>(h3, w6, pp);
    k_sum_squash2<<<1152, 256, 0, stream>>>(pp, pcb, u);
    k_build_uhat<<<1152, 256, 0, stream>>>(u, Wd, uh);

    // iter 0: c = 0.1 exactly
    k_route_s0<<<dim3(144, 4), 256, 0, stream>>>(uh, sp);
    k_route_v<<<160, 256, 0, stream>>>(sp, v);
    // iter 1 (fused agree+softmax+s); logits were zero -> add=0, store for iter 2
    k_route_as<<<dim3(144, 4), 256, 0, stream>>>(lg, uh, v, sp, 0, 1);
    k_route_v<<<160, 256, 0, stream>>>(sp, v);
    // iter 2 (fused); last use of logits -> no store
    k_route_as<<<dim3(144, 4), 256, 0, stream>>>(lg, uh, v, sp, 1, 0);
    k_route_v<<<160, 256, 0, stream>>>(sp, out);
}